// Round 1
// 287.847 us; speedup vs baseline: 1.0045x; 1.0045x over previous
//
#include <hip/hip_runtime.h>
#include <hip/hip_bf16.h>

#define N_NODES 50000
#define N_EDGES 800000
#define CAP 64                       // max deg ~45 for Poisson(16) over 50K
#define NODE_GS_BLOCKS 1250          // node-role blocks (grid-stride, 5 batches)
#define BUCKET_BLOCKS (N_EDGES/256)  // 3125 exact

__device__ __forceinline__ unsigned short f2bf(float f) {
    union { float f; unsigned u; } t; t.f = f;
    unsigned r = t.u + 0x7FFF + ((t.u >> 16) & 1);   // RNE
    return (unsigned short)(r >> 16);
}

// ---------------------------------------------------------------------------
// Prep kernel, role-split:
//  node role (blocks 0..1249): lin1 + self-connection.
//    v2: W1s/W1v columns held in 64 VGPRs (loaded once, coalesced);
//    x broadcasts vectorized to ds_read_b128; only species-dependent Wsc
//    stays in LDS (conflict-free b32). Cuts LDS wave-instrs/node ~2.7x —
//    prep was LDS-issue bound (~100+ us, hiding just under agg in top-k).
//  bucket role: reverse-CSR build, edge id only (src resolved in agg).
// ---------------------------------------------------------------------------
__global__ __launch_bounds__(256) void prep_kernel(
    const float* __restrict__ x, const float* __restrict__ attr,
    const float* __restrict__ W1s, const float* __restrict__ W1v,
    const float* __restrict__ Wscs, const float* __restrict__ Wscv,
    const int* __restrict__ eidx,
    int* __restrict__ counts, int* __restrict__ bucket,
    unsigned short* __restrict__ ysvh, float* __restrict__ out)
{
    // node role layout: x[0..1023] | Wscs[1024..5119] | Wscv[5120..9215]
    __shared__ float shm[9216];
    const int tid = threadIdx.x;

    if (blockIdx.x < NODE_GS_BLOCKS) {
        // ---------------- node role ----------------
        const int nl = tid >> 5;
        const int w  = tid & 31;

        // W1 columns (column w, all u) in registers — loaded once, coalesced
        float w1s[32], w1v[32];
        #pragma unroll
        for (int u = 0; u < 32; ++u) {
            w1s[u] = W1s[u*32 + w];
            w1v[u] = W1v[u*32 + w];
        }
        // stage Wsc into LDS (1024 float4 each)
        #pragma unroll
        for (int i = 0; i < 4; ++i) {
            ((float4*)(shm + 1024))[tid + i*256] = ((const float4*)Wscs)[tid + i*256];
            ((float4*)(shm + 5120))[tid + i*256] = ((const float4*)Wscv)[tid + i*256];
        }

        const float l1n = 0.17677669529663687f;   // 1/sqrt(32)
        const float scn = 0.08838834764831843f;   // 1/sqrt(128)

        for (int batch = 0; batch < 5; ++batch) {
            const int node0 = blockIdx.x * 40 + batch * 8;
            __syncthreads();   // protect shm x-region (covers Wsc staging too)
            ((float4*)shm)[tid] = ((const float4*)(x + (long)node0 * 128))[tid];
            __syncthreads();

            const int node = node0 + nl;
            const float* at = attr + (long)node * 4;
            int sp = 0;
            if (at[1] > 0.5f) sp = 1;
            if (at[2] > 0.5f) sp = 2;
            if (at[3] > 0.5f) sp = 3;

            const float* lx   = shm + nl * 128;
            const float* lscs = shm + 1024 + sp * 32;
            const float* lscv = shm + 5120 + sp * 32;

            float ys = 0.f, yv0 = 0.f, yv1 = 0.f, yv2 = 0.f;
            float ss = 0.f, sv0 = 0.f, sv1 = 0.f, sv2 = 0.f;
            #pragma unroll
            for (int u4 = 0; u4 < 8; ++u4) {
                // broadcast b128 reads (all 32 lanes of the group, same addr)
                const float4 xs4 = ((const float4*)lx)[u4];
                const float4 q0  = ((const float4*)(lx + 32))[u4*3 + 0];
                const float4 q1  = ((const float4*)(lx + 32))[u4*3 + 1];
                const float4 q2  = ((const float4*)(lx + 32))[u4*3 + 2];
                const float xsv[4]  = {xs4.x, xs4.y, xs4.z, xs4.w};
                const float xvv[12] = {q0.x,q0.y,q0.z,q0.w,
                                       q1.x,q1.y,q1.z,q1.w,
                                       q2.x,q2.y,q2.z,q2.w};
                #pragma unroll
                for (int j = 0; j < 4; ++j) {
                    const int u = u4*4 + j;
                    const float wss = lscs[u*128 + w];   // conflict-free b32
                    const float wsv = lscv[u*128 + w];
                    ys  += xsv[j] * w1s[u];
                    yv0 += xvv[3*j+0] * w1v[u];
                    yv1 += xvv[3*j+1] * w1v[u];
                    yv2 += xvv[3*j+2] * w1v[u];
                    ss  += xsv[j] * wss;
                    sv0 += xvv[3*j+0] * wsv;
                    sv1 += xvv[3*j+1] * wsv;
                    sv2 += xvv[3*j+2] * wsv;
                }
            }

            uint2 pk;
            pk.x = (unsigned)f2bf(ys  * l1n) | ((unsigned)f2bf(yv0 * l1n) << 16);
            pk.y = (unsigned)f2bf(yv1 * l1n) | ((unsigned)f2bf(yv2 * l1n) << 16);
            *(uint2*)(ysvh + (long)node * 128 + w * 4) = pk;

            float* op = out + (long)node * 128;
            op[w] = ss * scn;
            op[32 + 3*w + 0] = sv0 * scn;
            op[32 + 3*w + 1] = sv1 * scn;
            op[32 + 3*w + 2] = sv2 * scn;
        }
    } else {
        // ---------------- bucket role (edge id only) ----------------
        const int e = (blockIdx.x - NODE_GS_BLOCKS) * 256 + tid;
        const int dst = eidx[N_EDGES + e];
        const int slot = atomicAdd(&counts[dst], 1);
        if (slot < CAP) bucket[(long)dst * CAP + slot] = e;
    }
}

// ---------------------------------------------------------------------------
// Aggregation: 8 nodes / 256-thread block, 32 lanes per node-group. FiLM
// computed in-kernel lane-parallel (prologue) into LDS; loop body: broadcast
// ds_read of {h',attr} + prefetched ysv gathers ONLY. 4 edges/iter with the
// next EIGHT gathers in flight (v2: depth 4 -> 8; gathers are L2-miss /
// L3-latency bound at 2.1 TB/s — deepen MLP to convert stall into overlap).
// ---------------------------------------------------------------------------
__global__ __launch_bounds__(256) void agg_kernel(
    const float* __restrict__ ee, const float* __restrict__ eattr,
    const int* __restrict__ eidx,
    const float* __restrict__ fcw1, const float* __restrict__ fcw2,
    const float* __restrict__ W2s, const float* __restrict__ W2v,
    const unsigned short* __restrict__ ysvh,
    const int* __restrict__ counts, const int* __restrict__ bucket,
    float* __restrict__ out)
{
    __shared__ float hrec[8][32 * 12];  // 12 KB: per group, per slot {h'[8], attr[4]}
    __shared__ float mid[8][256];       // 8 KB

    const int tid = threadIdx.x;
    const int nl = tid >> 5;
    const int u  = tid & 31;
    const int node = blockIdx.x * 8 + nl;
    const float inv_sqrt8 = 0.35355339059327373f;

    // fc2 fragment: f2r[j][q] = fcw2[j*128 + q*32 + u]
    float f2r[8][4];
    #pragma unroll
    for (int j = 0; j < 8; ++j) {
        f2r[j][0] = fcw2[j*128 + u];
        f2r[j][1] = fcw2[j*128 + 32 + u];
        f2r[j][2] = fcw2[j*128 + 64 + u];
        f2r[j][3] = fcw2[j*128 + 96 + u];
    }

    const int cnt = min(counts[node], CAP);
    int e0 = bucket[(long)node * CAP + u];
    const bool dummy = (u >= cnt);
    if (dummy) e0 = 0;
    int s0 = eidx[e0];                  // src for this slot (gather)

    // ---- prologue: lane u computes FiLM h' for its own slot's edge ----
    {
        const float4 ea = ((const float4*)(ee + (long)e0 * 8))[0];
        const float4 eb = ((const float4*)(ee + (long)e0 * 8))[1];
        const float4 at = ((const float4*)eattr)[e0];
        const float eev[8] = {ea.x, ea.y, ea.z, ea.w, eb.x, eb.y, eb.z, eb.w};
        float* hr = hrec[nl] + u * 12;
        float h[8];
        #pragma unroll
        for (int j = 0; j < 8; ++j) {
            float pre = 0.f;
            #pragma unroll
            for (int b = 0; b < 8; ++b) pre += eev[b] * fcw1[b*8 + j];
            pre *= inv_sqrt8;
            const float s = pre / (1.f + __expf(-pre)) * inv_sqrt8;
            h[j] = dummy ? 0.f : s;     // h'=0 kills every term of a dummy slot
        }
        ((float4*)hr)[0] = make_float4(h[0], h[1], h[2], h[3]);
        ((float4*)hr)[1] = make_float4(h[4], h[5], h[6], h[7]);
        ((float4*)hr)[2] = at;
        // no barrier: written and read by the same 32-lane group (wave-sync)
    }

    float msa = 0.f, msb = 0.f;
    float va0 = 0.f, va1 = 0.f, va2 = 0.f;
    float vb0 = 0.f, vb1 = 0.f, vb2 = 0.f;

    #define ACCUM(HA, HB, AT, Y)                                             \
    {                                                                        \
        const float es = __uint_as_float((Y).x << 16);                       \
        const float ex = __uint_as_float((Y).x & 0xffff0000u);               \
        const float ey = __uint_as_float((Y).y << 16);                       \
        const float ez = __uint_as_float((Y).y & 0xffff0000u);               \
        const float hh[8] = {HA.x,HA.y,HA.z,HA.w,HB.x,HB.y,HB.z,HB.w};       \
        float w00=0.f, w01=0.f, w10=0.f, w11=0.f;                            \
        _Pragma("unroll")                                                    \
        for (int j = 0; j < 8; ++j) {                                        \
            w00 += hh[j]*f2r[j][0]; w01 += hh[j]*f2r[j][1];                  \
            w10 += hh[j]*f2r[j][2]; w11 += hh[j]*f2r[j][3];                  \
        }                                                                    \
        const float a0 = AT.x, a1x = AT.y, a1y = AT.z, a1z = AT.w;           \
        msa += w00 * es * a0;                                                \
        msb += w11 * (ex*a1x + ey*a1y + ez*a1z);                             \
        const float t = w01 * es;                                            \
        va0 += t*a1x; va1 += t*a1y; va2 += t*a1z;                            \
        const float s = w10 * a0;                                            \
        vb0 += s*ex; vb1 += s*ey; vb2 += s*ez;                               \
    }

    #define GATHER(SLOT) \
        (*(const uint2*)(ysvh + (long)__shfl(s0, (SLOT), 32) * 128 + u * 4))

    // ---- main loop: 4 edges/iter, next 8 gathers in flight (ping-pong) ----
    const int c0 = min(cnt, 32);
    {
        uint2 y0 = GATHER(0), y1 = GATHER(1), y2 = GATHER(2), y3 = GATHER(3);
        uint2 y4 = GATHER(4), y5 = GATHER(5), y6 = GATHER(6), y7 = GATHER(7);
        for (int k = 0; k < c0; k += 4) {
            const int kn = (k + 8) & 31;            // wrap: dummy-safe
            const uint2 n0 = GATHER(kn);
            const uint2 n1 = GATHER(kn + 1);
            const uint2 n2 = GATHER(kn + 2);
            const uint2 n3 = GATHER(kn + 3);
            const float4* h0p = (const float4*)(hrec[nl] + (k + 0) * 12);
            const float4* h1p = (const float4*)(hrec[nl] + (k + 1) * 12);
            const float4* h2p = (const float4*)(hrec[nl] + (k + 2) * 12);
            const float4* h3p = (const float4*)(hrec[nl] + (k + 3) * 12);
            const float4 A0 = h0p[0], B0 = h0p[1], T0 = h0p[2];
            const float4 A1 = h1p[0], B1 = h1p[1], T1 = h1p[2];
            const float4 A2 = h2p[0], B2 = h2p[1], T2 = h2p[2];
            const float4 A3 = h3p[0], B3 = h3p[1], T3 = h3p[2];
            ACCUM(A0, B0, T0, y0)
            ACCUM(A1, B1, T1, y1)
            ACCUM(A2, B2, T2, y2)
            ACCUM(A3, B3, T3, y3)
            y0 = y4; y1 = y5; y2 = y6; y3 = y7;
            y4 = n0; y5 = n1; y6 = n2; y7 = n3;
        }
    }

    // ---- rare tail (cnt > 32): redundant per-lane FiLM ----
    if (cnt > 32) {
        int be = bucket[(long)node * CAP + 32 + u];
        if (32 + u >= cnt) be = 0;
        for (int k = 32; k < cnt; ++k) {
            const int e = __shfl(be, k - 32, 32);
            const int s = eidx[e];
            const float4 ea = ((const float4*)(ee + (long)e * 8))[0];
            const float4 eb = ((const float4*)(ee + (long)e * 8))[1];
            const float4 at = ((const float4*)eattr)[e];
            const float eev[8] = {ea.x, ea.y, ea.z, ea.w, eb.x, eb.y, eb.z, eb.w};
            float h[8];
            #pragma unroll
            for (int j = 0; j < 8; ++j) {
                float pre = 0.f;
                #pragma unroll
                for (int b = 0; b < 8; ++b) pre += eev[b] * fcw1[b*8 + j];
                pre *= inv_sqrt8;
                h[j] = pre / (1.f + __expf(-pre)) * inv_sqrt8;
            }
            const float4 HA = make_float4(h[0], h[1], h[2], h[3]);
            const float4 HB = make_float4(h[4], h[5], h[6], h[7]);
            const uint2 y = *(const uint2*)(ysvh + (long)s * 128 + u * 4);
            ACCUM(HA, HB, at, y)
        }
    }
    #undef GATHER
    #undef ACCUM

    msb *= 0.5773502691896258f;  // INV_SQRT3

    // ---- lin2 epilogue via mid-LDS transpose (intra-group, no barrier) ----
    float* m = mid[nl];
    m[u]       = msa;
    m[32 + u]  = msb;
    m[64  + u*3 + 0] = va0;  m[64  + u*3 + 1] = va1;  m[64  + u*3 + 2] = va2;
    m[160 + u*3 + 0] = vb0;  m[160 + u*3 + 1] = vb1;  m[160 + u*3 + 2] = vb2;

    float os = 0.f, ov0 = 0.f, ov1 = 0.f, ov2 = 0.f;
    #pragma unroll 8
    for (int q = 0; q < 32; ++q) {
        const float wsa = W2s[q*32 + u];
        const float wsb = W2s[(32 + q)*32 + u];
        os += m[q] * wsa + m[32 + q] * wsb;
        const float wva = W2v[q*32 + u];
        const float wvb = W2v[(32 + q)*32 + u];
        ov0 += m[64 + q*3 + 0] * wva + m[160 + q*3 + 0] * wvb;
        ov1 += m[64 + q*3 + 1] * wva + m[160 + q*3 + 1] * wvb;
        ov2 += m[64 + q*3 + 2] * wva + m[160 + q*3 + 2] * wvb;
    }

    const float sc = 0.03125f;  // (1/sqrt 16) * (1/sqrt 64)
    float* op = out + (long)node * 128;
    op[u]            += os  * sc;
    op[32 + 3*u + 0] += ov0 * sc;
    op[32 + 3*u + 1] += ov1 * sc;
    op[32 + 3*u + 2] += ov2 * sc;
}

extern "C" void kernel_launch(void* const* d_in, const int* in_sizes, int n_in,
                              void* d_out, int out_size, void* d_ws, size_t ws_size,
                              hipStream_t stream) {
    const float* x     = (const float*)d_in[0];
    const float* attr  = (const float*)d_in[1];
    const float* ee    = (const float*)d_in[2];
    const float* eattr = (const float*)d_in[3];
    const int*   eidx  = (const int*)  d_in[4];
    const float* W1s   = (const float*)d_in[5];
    const float* W1v   = (const float*)d_in[6];
    const float* fcw1  = (const float*)d_in[7];
    const float* fcw2  = (const float*)d_in[8];
    const float* W2s   = (const float*)d_in[9];
    const float* W2v   = (const float*)d_in[10];
    const float* Wscs  = (const float*)d_in[11];
    const float* Wscv  = (const float*)d_in[12];

    float* out = (float*)d_out;

    // workspace layout (16-B aligned)
    unsigned short* ysvh = (unsigned short*)d_ws;            // 50000*128 bf16 = 12.8 MB
    int*   counts = (int*)(ysvh + (long)N_NODES * 128);      // 50000 i32
    int*   bucket = counts + N_NODES;                        // 50000*64 i32 = 12.8 MB

    hipMemsetAsync(counts, 0, N_NODES * sizeof(int), stream);
    prep_kernel<<<NODE_GS_BLOCKS + BUCKET_BLOCKS, 256, 0, stream>>>(
        x, attr, W1s, W1v, Wscs, Wscv, eidx, counts, bucket, ysvh, out);
    agg_kernel<<<N_NODES/8, 256, 0, stream>>>(ee, eattr, eidx, fcw1, fcw2,
                                              W2s, W2v, ysvh, counts, bucket, out);
}